// Round 1
// baseline (593.489 us; speedup 1.0000x reference)
//
#include <hip/hip_runtime.h>

typedef unsigned short ushort_t;
typedef __bf16 b16x8 __attribute__((ext_vector_type(8)));
typedef float f32x4 __attribute__((ext_vector_type(4)));
typedef unsigned short u16x8 __attribute__((ext_vector_type(8)));

#define DEVINL __device__ __forceinline__

constexpr int B = 16, S = 512, F = 1024;
constexpr int M_ROWS = B * S;                    // 8192
constexpr size_t NX = (size_t)M_ROWS * F;        // 8,388,608 elems per modality
constexpr size_t NW = (size_t)F * (2 * F);       // 2,097,152 elems per branch (WT: 1024x2048)
constexpr size_t NSC = (size_t)3 * B * S * S;    // 12,582,912 score elems

// ---------- bf16 helpers (RNE) ----------
DEVINL ushort_t f2bf(float f) {
  unsigned int u = __builtin_bit_cast(unsigned int, f);
  u += 0x7FFFu + ((u >> 16) & 1u);
  return (ushort_t)(u >> 16);
}
DEVINL float bf2f(ushort_t h) {
  unsigned int u = ((unsigned int)h) << 16;
  return __builtin_bit_cast(float, u);
}

// ---------- async global->LDS (16B per lane) ----------
DEVINL void gload_lds16(const void* g, void* l) {
  __builtin_amdgcn_global_load_lds(
      (__attribute__((address_space(1))) void*)(g),
      (__attribute__((address_space(3))) void*)(l), 16, 0, 0);
}

// stage a 128x32 bf16 tile (row-major, ld elements) into linear LDS [128][32]
DEVINL void stage_tile(ushort_t* lds, const ushort_t* src, int ld, int tid) {
  int wave = tid >> 6;
#pragma unroll
  for (int it = 0; it < 2; ++it) {
    int c = it * 256 + tid;                       // chunk = 16B = 8 bf16
    const ushort_t* g = src + (size_t)(c >> 2) * ld + (c & 3) * 8;
    ushort_t* l = lds + (size_t)(it * 256 + wave * 64) * 8;  // wave-uniform base
    gload_lds16(g, l);
  }
}

// A/B fragment: lane holds row (rb + lane&15), k = (lane>>4)*8 .. +8
DEVINL b16x8 frag_ld(const ushort_t* lds, int rb, int lane) {
  return *(const b16x8*)(lds + (size_t)(rb + (lane & 15)) * 32 + (lane >> 4) * 8);
}

DEVINL f32x4 mfma16(b16x8 a, b16x8 b, f32x4 c) {
  return __builtin_amdgcn_mfma_f32_16x16x32_bf16(a, b, c, 0, 0, 0);
}

// ---------- kernel 1: split t/v/a into bf16 hi/lo + per-batch transposed hi ----------
__global__ __launch_bounds__(256) void split_x_kernel(
    const float* __restrict__ v, const float* __restrict__ t, const float* __restrict__ a,
    ushort_t* __restrict__ xhi, ushort_t* __restrict__ xlo, ushort_t* __restrict__ xT) {
  __shared__ ushort_t tile[64][65];
  int mod = blockIdx.z;
  const float* src = (mod == 0) ? v : (mod == 1 ? t : a);
  int b = blockIdx.y;
  int s0 = (blockIdx.x >> 4) * 64;
  int f0 = (blockIdx.x & 15) * 64;
  int tid = threadIdx.x;
  ushort_t* xh = xhi + mod * NX;
  ushort_t* xl = xlo + mod * NX;
  ushort_t* xt = xT + mod * NX;
  int fl = (tid & 15) * 4;
#pragma unroll
  for (int r = 0; r < 4; ++r) {
    int sl = (tid >> 4) + r * 16;
    size_t gidx = ((size_t)(b * S + s0 + sl)) * F + f0 + fl;
    float4 x = *(const float4*)(src + gidx);
    ushort_t h0 = f2bf(x.x), h1 = f2bf(x.y), h2 = f2bf(x.z), h3 = f2bf(x.w);
    *(ushort4*)(xh + gidx) = make_ushort4(h0, h1, h2, h3);
    *(ushort4*)(xl + gidx) = make_ushort4(
        f2bf(x.x - bf2f(h0)), f2bf(x.y - bf2f(h1)),
        f2bf(x.z - bf2f(h2)), f2bf(x.w - bf2f(h3)));
    tile[sl][fl] = h0; tile[sl][fl + 1] = h1; tile[sl][fl + 2] = h2; tile[sl][fl + 3] = h3;
  }
  __syncthreads();
#pragma unroll
  for (int r = 0; r < 4; ++r) {
    int flr = (tid >> 4) + r * 16;
    int sl4 = (tid & 15) * 4;
    ushort4 o = make_ushort4(tile[sl4][flr], tile[sl4 + 1][flr],
                             tile[sl4 + 2][flr], tile[sl4 + 3][flr]);
    size_t tidx = ((size_t)(b * F + f0 + flr)) * S + s0 + sl4;
    *(ushort4*)(xt + tidx) = o;
  }
}

// ---------- kernel 2: W (2048x1024) -> WT hi/lo (1024x2048) ----------
__global__ __launch_bounds__(256) void split_w_kernel(
    const float* __restrict__ w0, const float* __restrict__ w1, const float* __restrict__ w2,
    ushort_t* __restrict__ wthi, ushort_t* __restrict__ wtlo) {
  __shared__ ushort_t th[64][65];
  __shared__ ushort_t tl[64][65];
  int br = blockIdx.z;
  const float* w = (br == 0) ? w0 : (br == 1 ? w1 : w2);
  int g0 = blockIdx.x * 64;   // cols of W (rows of WT)
  int f0 = blockIdx.y * 64;   // rows of W
  int tid = threadIdx.x;
  int gl = (tid & 15) * 4;
#pragma unroll
  for (int r = 0; r < 4; ++r) {
    int fl = (tid >> 4) + r * 16;
    float4 x = *(const float4*)(w + (size_t)(f0 + fl) * F + g0 + gl);
    ushort_t h0 = f2bf(x.x), h1 = f2bf(x.y), h2 = f2bf(x.z), h3 = f2bf(x.w);
    th[fl][gl] = h0; th[fl][gl + 1] = h1; th[fl][gl + 2] = h2; th[fl][gl + 3] = h3;
    tl[fl][gl] = f2bf(x.x - bf2f(h0));
    tl[fl][gl + 1] = f2bf(x.y - bf2f(h1));
    tl[fl][gl + 2] = f2bf(x.z - bf2f(h2));
    tl[fl][gl + 3] = f2bf(x.w - bf2f(h3));
  }
  __syncthreads();
  ushort_t* oh = wthi + br * NW;
  ushort_t* ol = wtlo + br * NW;
#pragma unroll
  for (int r = 0; r < 4; ++r) {
    int glr = (tid >> 4) + r * 16;
    int fl4 = (tid & 15) * 4;
    size_t o = (size_t)(g0 + glr) * (2 * F) + f0 + fl4;
    *(ushort4*)(oh + o) = make_ushort4(th[fl4][glr], th[fl4 + 1][glr],
                                       th[fl4 + 2][glr], th[fl4 + 3][glr]);
    *(ushort4*)(ol + o) = make_ushort4(tl[fl4][glr], tl[fl4 + 1][glr],
                                       tl[fl4 + 2][glr], tl[fl4 + 3][glr]);
  }
}

// ---------- kernel 3: Feat = tanh(concat(x1,x2) @ W + b), split-bf16 3-MFMA ----------
__global__ __launch_bounds__(256) void feat_gemm_kernel(
    const ushort_t* __restrict__ xhi, const ushort_t* __restrict__ xlo,
    const ushort_t* __restrict__ wthi, const ushort_t* __restrict__ wtlo,
    const float* __restrict__ b0, const float* __restrict__ b1, const float* __restrict__ b2,
    ushort_t* __restrict__ fhi, ushort_t* __restrict__ flo) {
  constexpr int M1[3] = {1, 1, 2};   // t, t, a
  constexpr int M2[3] = {0, 2, 0};   // v, a, v
  __shared__ __attribute__((aligned(16))) ushort_t lds[4 * 4096];
  ushort_t* Ah = lds;           ushort_t* Al = lds + 4096;
  ushort_t* Bh = lds + 8192;    ushort_t* Bl = lds + 12288;
  int br = blockIdx.z;
  int gm0 = blockIdx.x * 128;
  int gn0 = blockIdx.y * 128;
  int tid = threadIdx.x, lane = tid & 63, wave = tid >> 6;
  int wr = (wave >> 1) * 64, wc = (wave & 1) * 64;
  const ushort_t* x1h = xhi + M1[br] * NX;
  const ushort_t* x1l = xlo + M1[br] * NX;
  const ushort_t* x2h = xhi + M2[br] * NX;
  const ushort_t* x2l = xlo + M2[br] * NX;
  const ushort_t* wh = wthi + br * NW;
  const ushort_t* wl = wtlo + br * NW;
  f32x4 acc[4][4] = {};
  for (int k0 = 0; k0 < 2 * F; k0 += 32) {
    const ushort_t* ah = (k0 < F) ? x1h : x2h;
    const ushort_t* al = (k0 < F) ? x1l : x2l;
    int ke = k0 & (F - 1);
    stage_tile(Ah, ah + (size_t)gm0 * F + ke, F, tid);
    stage_tile(Al, al + (size_t)gm0 * F + ke, F, tid);
    stage_tile(Bh, wh + (size_t)gn0 * (2 * F) + k0, 2 * F, tid);
    stage_tile(Bl, wl + (size_t)gn0 * (2 * F) + k0, 2 * F, tid);
    __syncthreads();
    b16x8 afh[4], afl[4], bfh[4], bfl[4];
#pragma unroll
    for (int i = 0; i < 4; ++i) {
      afh[i] = frag_ld(Ah, wr + i * 16, lane);
      afl[i] = frag_ld(Al, wr + i * 16, lane);
      bfh[i] = frag_ld(Bh, wc + i * 16, lane);
      bfl[i] = frag_ld(Bl, wc + i * 16, lane);
    }
#pragma unroll
    for (int i = 0; i < 4; ++i)
#pragma unroll
      for (int j = 0; j < 4; ++j) {
        acc[i][j] = mfma16(afh[i], bfh[j], acc[i][j]);
        acc[i][j] = mfma16(afh[i], bfl[j], acc[i][j]);
        acc[i][j] = mfma16(afl[i], bfh[j], acc[i][j]);
      }
    __syncthreads();
  }
  const float* bias = (br == 0) ? b0 : (br == 1 ? b1 : b2);
  ushort_t* oh = fhi + br * NX;
  ushort_t* ol = flo + br * NX;
#pragma unroll
  for (int i = 0; i < 4; ++i)
#pragma unroll
    for (int j = 0; j < 4; ++j)
#pragma unroll
      for (int r = 0; r < 4; ++r) {
        int row = gm0 + wr + i * 16 + (lane >> 4) * 4 + r;
        int col = gn0 + wc + j * 16 + (lane & 15);
        float val = tanhf(acc[i][j][r] + bias[col]);
        ushort_t h = f2bf(val);
        size_t o = (size_t)row * F + col;
        oh[o] = h;
        ol[o] = f2bf(val - bf2f(h));
      }
}

// ---------- kernel 4: scores = q @ feat^T  (split-bf16 3-MFMA), fp32 out ----------
__global__ __launch_bounds__(256) void scores_gemm_kernel(
    const ushort_t* __restrict__ xhi, const ushort_t* __restrict__ xlo,
    const ushort_t* __restrict__ fhi, const ushort_t* __restrict__ flo,
    float* __restrict__ scores) {
  constexpr int QM[3] = {2, 0, 1};   // a, v, t
  __shared__ __attribute__((aligned(16))) ushort_t lds[4 * 4096];
  ushort_t* Ah = lds;           ushort_t* Al = lds + 4096;
  ushort_t* Bh = lds + 8192;    ushort_t* Bl = lds + 12288;
  int z = blockIdx.z;
  int br = z >> 4, b = z & 15;
  int gm0 = blockIdx.x * 128;   // q rows
  int gn0 = blockIdx.y * 128;   // key rows
  int tid = threadIdx.x, lane = tid & 63, wave = tid >> 6;
  int wr = (wave >> 1) * 64, wc = (wave & 1) * 64;
  const ushort_t* qh = xhi + QM[br] * NX + (size_t)(b * S) * F;
  const ushort_t* ql = xlo + QM[br] * NX + (size_t)(b * S) * F;
  const ushort_t* kh = fhi + br * NX + (size_t)(b * S) * F;
  const ushort_t* kl = flo + br * NX + (size_t)(b * S) * F;
  f32x4 acc[4][4] = {};
  for (int k0 = 0; k0 < F; k0 += 32) {
    stage_tile(Ah, qh + (size_t)gm0 * F + k0, F, tid);
    stage_tile(Al, ql + (size_t)gm0 * F + k0, F, tid);
    stage_tile(Bh, kh + (size_t)gn0 * F + k0, F, tid);
    stage_tile(Bl, kl + (size_t)gn0 * F + k0, F, tid);
    __syncthreads();
    b16x8 afh[4], afl[4], bfh[4], bfl[4];
#pragma unroll
    for (int i = 0; i < 4; ++i) {
      afh[i] = frag_ld(Ah, wr + i * 16, lane);
      afl[i] = frag_ld(Al, wr + i * 16, lane);
      bfh[i] = frag_ld(Bh, wc + i * 16, lane);
      bfl[i] = frag_ld(Bl, wc + i * 16, lane);
    }
#pragma unroll
    for (int i = 0; i < 4; ++i)
#pragma unroll
      for (int j = 0; j < 4; ++j) {
        acc[i][j] = mfma16(afh[i], bfh[j], acc[i][j]);
        acc[i][j] = mfma16(afh[i], bfl[j], acc[i][j]);
        acc[i][j] = mfma16(afl[i], bfh[j], acc[i][j]);
      }
    __syncthreads();
  }
  float* out = scores + (size_t)z * S * S;
#pragma unroll
  for (int i = 0; i < 4; ++i)
#pragma unroll
    for (int j = 0; j < 4; ++j)
#pragma unroll
      for (int r = 0; r < 4; ++r) {
        int row = gm0 + wr + i * 16 + (lane >> 4) * 4 + r;
        int col = gn0 + wc + j * 16 + (lane & 15);
        out[(size_t)row * S + col] = acc[i][j][r];
      }
}

// ---------- kernel 5: row softmax (512), fp32 in -> bf16 p ----------
__global__ __launch_bounds__(256) void softmax_kernel(
    const float* __restrict__ scores, ushort_t* __restrict__ p) {
  int wave = threadIdx.x >> 6, lane = threadIdx.x & 63;
  int row = blockIdx.x * 4 + wave;
  const float* src = scores + (size_t)row * S;
  float4 v0 = *(const float4*)(src + lane * 8);
  float4 v1 = *(const float4*)(src + lane * 8 + 4);
  float m = fmaxf(fmaxf(fmaxf(v0.x, v0.y), fmaxf(v0.z, v0.w)),
                  fmaxf(fmaxf(v1.x, v1.y), fmaxf(v1.z, v1.w)));
#pragma unroll
  for (int d = 1; d < 64; d <<= 1) m = fmaxf(m, __shfl_xor(m, d));
  float e[8] = {expf(v0.x - m), expf(v0.y - m), expf(v0.z - m), expf(v0.w - m),
                expf(v1.x - m), expf(v1.y - m), expf(v1.z - m), expf(v1.w - m)};
  float s = ((e[0] + e[1]) + (e[2] + e[3])) + ((e[4] + e[5]) + (e[6] + e[7]));
#pragma unroll
  for (int d = 1; d < 64; d <<= 1) s += __shfl_xor(s, d);
  float inv = 1.0f / s;
  u16x8 o;
#pragma unroll
  for (int j = 0; j < 8; ++j) o[j] = f2bf(e[j] * inv);
  *(u16x8*)(p + (size_t)row * S + lane * 8) = o;
}

// ---------- kernel 6: O = (p @ q) * feat, plain bf16 MFMA, fp32 out ----------
__global__ __launch_bounds__(256) void pv_gemm_kernel(
    const ushort_t* __restrict__ p, const ushort_t* __restrict__ xT,
    const ushort_t* __restrict__ fhi, const ushort_t* __restrict__ flo,
    float* __restrict__ out) {
  constexpr int QM[3] = {2, 0, 1};
  __shared__ __attribute__((aligned(16))) ushort_t lds[2 * 4096];
  ushort_t* Ah = lds;
  ushort_t* Bh = lds + 4096;
  int z = blockIdx.z;
  int br = z >> 4, b = z & 15;
  int gm0 = blockIdx.x * 128;   // q rows
  int gn0 = blockIdx.y * 128;   // f cols
  int tid = threadIdx.x, lane = tid & 63, wave = tid >> 6;
  int wr = (wave >> 1) * 64, wc = (wave & 1) * 64;
  const ushort_t* pa = p + (size_t)z * S * S;
  const ushort_t* qt = xT + QM[br] * NX + (size_t)b * F * S;   // [f][s]
  f32x4 acc[4][4] = {};
  for (int k0 = 0; k0 < S; k0 += 32) {
    stage_tile(Ah, pa + (size_t)gm0 * S + k0, S, tid);
    stage_tile(Bh, qt + (size_t)gn0 * S + k0, S, tid);
    __syncthreads();
    b16x8 af[4], bf_[4];
#pragma unroll
    for (int i = 0; i < 4; ++i) {
      af[i] = frag_ld(Ah, wr + i * 16, lane);
      bf_[i] = frag_ld(Bh, wc + i * 16, lane);
    }
#pragma unroll
    for (int i = 0; i < 4; ++i)
#pragma unroll
      for (int j = 0; j < 4; ++j)
        acc[i][j] = mfma16(af[i], bf_[j], acc[i][j]);
    __syncthreads();
  }
  const ushort_t* eh = fhi + br * NX + (size_t)(b * S) * F;
  const ushort_t* el = flo + br * NX + (size_t)(b * S) * F;
#pragma unroll
  for (int i = 0; i < 4; ++i)
#pragma unroll
    for (int j = 0; j < 4; ++j)
#pragma unroll
      for (int r = 0; r < 4; ++r) {
        int row = gm0 + wr + i * 16 + (lane >> 4) * 4 + r;
        int col = gn0 + wc + j * 16 + (lane & 15);
        size_t fo = (size_t)row * F + col;
        float fe = bf2f(eh[fo]) + bf2f(el[fo]);
        out[(size_t)(b * S + row) * (3 * F) + br * F + col] = acc[i][j][r] * fe;
      }
}

extern "C" void kernel_launch(void* const* d_in, const int* in_sizes, int n_in,
                              void* d_out, int out_size, void* d_ws, size_t ws_size,
                              hipStream_t stream) {
  (void)in_sizes; (void)n_in; (void)out_size; (void)ws_size;
  const float* v = (const float*)d_in[0];
  const float* t = (const float*)d_in[1];
  const float* a = (const float*)d_in[2];
  const float* W_tv = (const float*)d_in[3];
  const float* b_tv = (const float*)d_in[4];
  const float* W_ta = (const float*)d_in[5];
  const float* b_ta = (const float*)d_in[6];
  const float* W_av = (const float*)d_in[7];
  const float* b_av = (const float*)d_in[8];
  float* out = (float*)d_out;

  // ws layout (336 MB total)
  ushort_t* xhi = (ushort_t*)d_ws;
  ushort_t* xlo = xhi + 3 * NX;
  ushort_t* xT = xlo + 3 * NX;
  ushort_t* wthi = xT + 3 * NX;
  ushort_t* wtlo = wthi + 3 * NW;
  ushort_t* fhi = wtlo + 3 * NW;
  ushort_t* flo = fhi + 3 * NX;
  float* scores = (float*)(flo + 3 * NX);
  ushort_t* pbuf = (ushort_t*)(scores + NSC);

  split_x_kernel<<<dim3(128, 16, 3), 256, 0, stream>>>(v, t, a, xhi, xlo, xT);
  split_w_kernel<<<dim3(16, 32, 3), 256, 0, stream>>>(W_tv, W_ta, W_av, wthi, wtlo);
  feat_gemm_kernel<<<dim3(64, 8, 3), 256, 0, stream>>>(xhi, xlo, wthi, wtlo,
                                                       b_tv, b_ta, b_av, fhi, flo);
  scores_gemm_kernel<<<dim3(4, 4, 48), 256, 0, stream>>>(xhi, xlo, fhi, flo, scores);
  softmax_kernel<<<dim3((3 * B * S) / 4), 256, 0, stream>>>(scores, pbuf);
  pv_gemm_kernel<<<dim3(4, 8, 48), 256, 0, stream>>>(pbuf, xT, fhi, flo, out);
}